// Round 1
// baseline (282.252 us; speedup 1.0000x reference)
//
#include <hip/hip_runtime.h>

#define EPSQ 1e-5f

typedef signed char i8;
using int4v = __attribute__((ext_vector_type(4))) int;

constexpr int DIM = 4096;

// ---------------------------------------------------------------------------
// async global->LDS, 16 B per lane. LDS dest = wave-uniform base + lane*16.
// ---------------------------------------------------------------------------
__device__ __forceinline__ void gload_lds16(const void* g, void* l) {
  __builtin_amdgcn_global_load_lds(
      (const __attribute__((address_space(1))) void*)(g),
      (__attribute__((address_space(3))) void*)(l), 16, 0, 0);
}

// ---------------------------------------------------------------------------
// k_prep, one launch, three block ranges:
//   [0, 4096)      : per-row symmetric i8 quant of X, rs[row] = max|x|/127
//   [4096, 6144)   : W1 = (i8)Vp   (exact, Vp is ternary)
//   [6144, 8192)   : partial sums of |T|, T=(V-Vp*cos)/sin  (only if bias!=0)
// ---------------------------------------------------------------------------
__global__ __launch_bounds__(256)
void k_prep(const float* __restrict__ X, const float* __restrict__ V,
            const float* __restrict__ Vp,
            const float* __restrict__ theta_p, const float* __restrict__ bias_p,
            i8* __restrict__ Xq, float* __restrict__ rs,
            i8* __restrict__ W1, float* __restrict__ partial) {
  __shared__ float wred[4];
  const int tid = threadIdx.x;
  const int b = blockIdx.x;
  if (b < 4096) {
    // ---- X row quantization ----
    const int row = b;
    const float4* Xr = (const float4*)(X + (size_t)row * DIM);
    float4 f[4];
    float mx = 0.0f;
    #pragma unroll
    for (int t = 0; t < 4; ++t) {
      f[t] = Xr[tid + t * 256];
      mx = fmaxf(mx, fmaxf(fmaxf(fabsf(f[t].x), fabsf(f[t].y)),
                           fmaxf(fabsf(f[t].z), fabsf(f[t].w))));
    }
    #pragma unroll
    for (int off = 32; off > 0; off >>= 1) mx = fmaxf(mx, __shfl_down(mx, off, 64));
    int lane = tid & 63, w = tid >> 6;
    if (lane == 0) wred[w] = mx;
    __syncthreads();
    mx = fmaxf(fmaxf(wred[0], wred[1]), fmaxf(wred[2], wred[3]));
    mx = fmaxf(mx, 1e-30f);
    float rsv = mx / 127.0f;
    if (tid == 0) rs[row] = rsv;
    float inv = 1.0f / rsv;
    char4* Xo = (char4*)(Xq + (size_t)row * DIM);
    #pragma unroll
    for (int t = 0; t < 4; ++t) {
      char4 qv;
      qv.x = (i8)fminf(fmaxf(rintf(f[t].x * inv), -127.0f), 127.0f);
      qv.y = (i8)fminf(fmaxf(rintf(f[t].y * inv), -127.0f), 127.0f);
      qv.z = (i8)fminf(fmaxf(rintf(f[t].z * inv), -127.0f), 127.0f);
      qv.w = (i8)fminf(fmaxf(rintf(f[t].w * inv), -127.0f), 127.0f);
      Xo[tid + t * 256] = qv;
    }
  } else if (b < 6144) {
    // ---- W1 = (i8)Vp, exact ternary ----
    const float4* Vp4 = (const float4*)Vp;
    char4* W1o = (char4*)W1;
    const int total4 = DIM * DIM / 4;
    const int stride = 2048 * 256;
    for (int i = (b - 4096) * 256 + tid; i < total4; i += stride) {
      float4 vp = Vp4[i];
      char4 w1;
      w1.x = (i8)vp.x; w1.y = (i8)vp.y; w1.z = (i8)vp.z; w1.w = (i8)vp.w;
      W1o[i] = w1;
    }
  } else {
    // ---- |T| partial sums (no atomic, no memset needed) ----
    if (bias_p[0] == 0.0f) return;
    float ct = cosf(theta_p[0]);
    float st = sinf(theta_p[0]);
    const float4* V4  = (const float4*)V;
    const float4* Vp4 = (const float4*)Vp;
    float acc = 0.0f;
    const int total4 = DIM * DIM / 4;
    const int stride = 2048 * 256;
    for (int i = (b - 6144) * 256 + tid; i < total4; i += stride) {
      float4 v = V4[i], vp = Vp4[i];
      acc += fabsf((v.x - vp.x * ct) / st) + fabsf((v.y - vp.y * ct) / st)
           + fabsf((v.z - vp.z * ct) / st) + fabsf((v.w - vp.w * ct) / st);
    }
    #pragma unroll
    for (int off = 32; off > 0; off >>= 1) acc += __shfl_down(acc, off, 64);
    int lane = tid & 63, w = tid >> 6;
    if (lane == 0) wred[w] = acc;
    __syncthreads();
    if (tid == 0) partial[b - 6144] = wred[0] + wred[1] + wred[2] + wred[3];
  }
}

// ---------------------------------------------------------------------------
// k_quantT: only runs when bias != 0. Reduces the 2048 partials to the mean,
// then W2 = clamp(round(T/mean), -1, 1) as i8.
// ---------------------------------------------------------------------------
__global__ __launch_bounds__(256)
void k_quantT(const float* __restrict__ V, const float* __restrict__ Vp,
              const float* __restrict__ theta_p, const float* __restrict__ bias_p,
              const float* __restrict__ partial, i8* __restrict__ W2) {
  if (bias_p[0] == 0.0f) return;
  __shared__ float wred[4];
  __shared__ float stot;
  const int tid = threadIdx.x;
  float s = 0.0f;
  #pragma unroll
  for (int i = 0; i < 8; ++i) s += partial[tid + i * 256];
  #pragma unroll
  for (int off = 32; off > 0; off >>= 1) s += __shfl_down(s, off, 64);
  int lane = tid & 63, w = tid >> 6;
  if (lane == 0) wred[w] = s;
  __syncthreads();
  if (tid == 0) stot = wred[0] + wred[1] + wred[2] + wred[3];
  __syncthreads();
  float mean = fmaxf(stot / 16777216.0f, EPSQ);
  float scale = 1.0f / mean;
  float ctv = cosf(theta_p[0]);
  float stv = sinf(theta_p[0]);
  const float4* V4  = (const float4*)V;
  const float4* Vp4 = (const float4*)Vp;
  char4* W2o = (char4*)W2;
  const int total4 = DIM * DIM / 4;
  const int stride = 2048 * 256;
  for (int i = blockIdx.x * 256 + tid; i < total4; i += stride) {
    float4 v = V4[i], vp = Vp4[i];
    char4 w2;
    w2.x = (i8)fminf(fmaxf(rintf(((v.x - vp.x * ctv) / stv) * scale), -1.0f), 1.0f);
    w2.y = (i8)fminf(fmaxf(rintf(((v.y - vp.y * ctv) / stv) * scale), -1.0f), 1.0f);
    w2.z = (i8)fminf(fmaxf(rintf(((v.z - vp.z * ctv) / stv) * scale), -1.0f), 1.0f);
    w2.w = (i8)fminf(fmaxf(rintf(((v.w - vp.w * ctv) / stv) * scale), -1.0f), 1.0f);
    W2o[i] = w2;
  }
}

// ---------------------------------------------------------------------------
// i8 MFMA GEMM, 256x256 tile, BK=128 bytes, 8 waves (2Mx4N), 128 KiB dbuf LDS.
// 8-phase-style schedule: raw s_barrier + explicit lgkmcnt/vmcnt (NO
// __syncthreads in the loop -> no forced vmcnt(0) drain at barriers).
// Per K-tile: 4 quadrant-phases x 16 MFMA; next tile fully staged at phase 0
// (8 global_load_lds/wave), single vmcnt(0) at phase 3 => ~3 phases of cover.
// Chunk-XOR LDS swizzle (verified 0 bank conflicts in the previous kernel).
// Internal pass loop fuses the sign-GEMM (bias!=0 only) and the main GEMM.
// ---------------------------------------------------------------------------
__global__ __launch_bounds__(512, 2)
void k_gemm(const i8* __restrict__ A, const i8* __restrict__ B1,
            const i8* __restrict__ B2, float* __restrict__ C,
            const float* __restrict__ rs, const float* __restrict__ theta_p,
            const float* __restrict__ bias_p) {
  __shared__ i8 sm[131072];   // [As0 32K | Bs0 32K | As1 32K | Bs1 32K]

  const int tid  = threadIdx.x;
  const int lane = tid & 63;
  const int w    = tid >> 6;
  const int l15  = lane & 15;
  const int kq   = lane >> 4;          // k-quad 0..3
  const int wm   = (w >> 2) * 128;     // 2 waves in M
  const int wn   = (w & 3) * 64;       // 4 waves in N
  const int bm   = blockIdx.y * 256;
  const int bn   = blockIdx.x * 256;

  // staging geometry: tile = 256 rows x 8 chunks(16B); 4 issue lines x 512 thr
  int offg[4];
  #pragma unroll
  for (int ln = 0; ln < 4; ++ln) {
    int p = ln * 512 + tid;
    int r = p >> 3;
    int c = (p & 7) ^ (r & 7);          // XOR chunk swizzle (store-side inverse)
    offg[ln] = r * DIM + c * 16;
  }

  const int swz0 = ((0 * 4 + kq) ^ (l15 & 7)) * 16;   // k-chunk swizzle, s=0
  const int swz1 = ((1 * 4 + kq) ^ (l15 & 7)) * 16;   // s=1
  const int arow = (wm + l15) * 128;
  const int brow = (wn + l15) * 128;

  const float biasv = bias_p[0];
  const int npass = (biasv != 0.0f) ? 2 : 1;
  const float ct = cosf(theta_p[0]);

  for (int pass = 0; pass < npass; ++pass) {
    const bool signp = (npass == 2 && pass == 0);
    const i8* Ag = A + (size_t)bm * DIM;
    const i8* Bg = (signp ? B2 : B1) + (size_t)bn * DIM;

    int4v acc[8][4] = {};

    // ---- prologue: stage tile 0 into buf0, full drain once ----
    #pragma unroll
    for (int ln = 0; ln < 4; ++ln) {
      const int sb = (ln * 512 + w * 64) * 16;   // wave-uniform LDS base
      gload_lds16(Ag + offg[ln], sm + sb);
      gload_lds16(Bg + offg[ln], sm + 32768 + sb);
    }
    asm volatile("s_waitcnt vmcnt(0)" ::: "memory");
    __builtin_amdgcn_s_barrier();

    #pragma unroll 2
    for (int t = 0; t < 32; ++t) {
      const i8* As = sm + (t & 1) * 65536;
      const i8* Bs = As + 32768;
      i8* Asta = sm + ((t + 1) & 1) * 65536;
      i8* Bsta = Asta + 32768;
      const bool dostage = (t + 1 < 32);
      const int ktn = (t + 1) * 128;

      int4v af[4][2], bf[2][2];
      #pragma unroll
      for (int q = 0; q < 4; ++q) {
        const int mh = q >> 1, nh = q & 1;     // quadrant order (0,0)(0,1)(1,0)(1,1)
        if (nh == 0) {                         // A frags reused across two phases
          #pragma unroll
          for (int i4 = 0; i4 < 4; ++i4) {
            af[i4][0] = *(const int4v*)(As + arow + (mh * 4 + i4) * 2048 + swz0);
            af[i4][1] = *(const int4v*)(As + arow + (mh * 4 + i4) * 2048 + swz1);
          }
        }
        #pragma unroll
        for (int j2 = 0; j2 < 2; ++j2) {
          bf[j2][0] = *(const int4v*)(Bs + brow + (nh * 2 + j2) * 2048 + swz0);
          bf[j2][1] = *(const int4v*)(Bs + brow + (nh * 2 + j2) * 2048 + swz1);
        }
        if (q == 0 && dostage) {
          // issue the whole next tile now; lands before the vmcnt at q==3
          #pragma unroll
          for (int ln = 0; ln < 4; ++ln) {
            const int sb = (ln * 512 + w * 64) * 16;
            gload_lds16(Ag + ktn + offg[ln], Asta + sb);
            gload_lds16(Bg + ktn + offg[ln], Bsta + sb);
          }
        }
        __builtin_amdgcn_s_barrier();
        asm volatile("s_waitcnt lgkmcnt(0)" ::: "memory");
        __builtin_amdgcn_sched_barrier(0);     // keep MFMA below the wait
        __builtin_amdgcn_s_setprio(1);
        #pragma unroll
        for (int i4 = 0; i4 < 4; ++i4) {
          #pragma unroll
          for (int j2 = 0; j2 < 2; ++j2) {
            acc[mh * 4 + i4][nh * 2 + j2] = __builtin_amdgcn_mfma_i32_16x16x64_i8(
                af[i4][0], bf[j2][0], acc[mh * 4 + i4][nh * 2 + j2], 0, 0, 0);
            acc[mh * 4 + i4][nh * 2 + j2] = __builtin_amdgcn_mfma_i32_16x16x64_i8(
                af[i4][1], bf[j2][1], acc[mh * 4 + i4][nh * 2 + j2], 0, 0, 0);
          }
        }
        __builtin_amdgcn_s_setprio(0);
        if (q == 3) asm volatile("s_waitcnt vmcnt(0)" ::: "memory");
        __builtin_amdgcn_s_barrier();
      }
    }

    // ---- epilogue. C/D layout: row = kq*4 + reg, col = lane&15 per 16x16 ----
    if (signp) {
      #pragma unroll
      for (int i = 0; i < 8; ++i) {
        int mbase = bm + wm + i * 16 + kq * 4;
        #pragma unroll
        for (int j = 0; j < 4; ++j) {
          int n = bn + wn + j * 16 + l15;
          #pragma unroll
          for (int r = 0; r < 4; ++r) {
            int v = acc[i][j][r];
            float s = (v > 0) ? 1.0f : ((v < 0) ? -1.0f : 0.0f);
            C[(size_t)(mbase + r) * DIM + n] = s * biasv;
          }
        }
      }
    } else {
      #pragma unroll
      for (int i = 0; i < 8; ++i) {
        int mbase = bm + wm + i * 16 + kq * 4;
        float sc[4];
        #pragma unroll
        for (int r = 0; r < 4; ++r) sc[r] = ct * rs[mbase + r];
        #pragma unroll
        for (int j = 0; j < 4; ++j) {
          int n = bn + wn + j * 16 + l15;
          #pragma unroll
          for (int r = 0; r < 4; ++r) {
            size_t idx = (size_t)(mbase + r) * DIM + n;
            float outv = sc[r] * (float)acc[i][j][r];
            if (npass == 2) outv += C[idx];    // add sign-term from pass 0
            C[idx] = outv;
          }
        }
      }
    }
  }
}

// ---------------------------------------------------------------------------
extern "C" void kernel_launch(void* const* d_in, const int* in_sizes, int n_in,
                              void* d_out, int out_size, void* d_ws, size_t ws_size,
                              hipStream_t stream) {
  const float* V     = (const float*)d_in[0];
  const float* Vp    = (const float*)d_in[1];
  const float* X     = (const float*)d_in[2];
  const float* theta = (const float*)d_in[3];
  const float* bias  = (const float*)d_in[4];
  float* out = (float*)d_out;

  const size_t SZ = (size_t)DIM * DIM;   // 16,777,216 elements
  char* ws = (char*)d_ws;
  float* rs      = (float*)ws;                    // 16 KiB row scales
  float* partial = (float*)(ws + 16384);          // 8 KiB |T| partials
  i8* Xq = (i8*)(ws + 16384 + 8192);              // 16 MiB
  i8* W1 = Xq + SZ;                               // 16 MiB (V_p i8, exact)
  i8* W2 = W1 + SZ;                               // 16 MiB (Tq i8, bias!=0 only)

  k_prep<<<8192, 256, 0, stream>>>(X, V, Vp, theta, bias, Xq, rs, W1, partial);
  k_quantT<<<2048, 256, 0, stream>>>(V, Vp, theta, bias, partial, W2);
  k_gemm<<<dim3(16, 16), 512, 0, stream>>>(Xq, W1, W2, out, rs, theta, bias);
}